// Round 6
// baseline (281.604 us; speedup 1.0000x reference)
//
#include <hip/hip_runtime.h>

// GraphPairClassifier v6: tetrahedral graphs => GCN collapses to an MLP.
//   deg=4 everywhere, norm=0.25 exact; conv1 makes all 4 node feats identical
//   per tet => convs 2/3 are dense layers, mean-pool = identity.
//   Row order r = 2*g + side makes the [h1|h2] concat free.
// Dtypes (established R0-R5): device inputs are FP32 (values bf16-quantized,
//   so f2bf on them is exact); output is FP32.
// Precision: activations carried as hi+lo bf16 pairs (weights exact bf16),
//   2 MFMAs per tile => ~fp32 logits.
// Workspace (clean, element-correct offsets):
//   buf0hi [0,12.8M) buf0lo [12.8,25.6M) buf1hi [25.6,38.4M) buf1lo [38.4,51.2M)
//   weights [51.2M, +1.13M)

typedef short short8 __attribute__((ext_vector_type(8)));
typedef float floatx4 __attribute__((ext_vector_type(4)));

__device__ __forceinline__ unsigned short f2bf(float f) {
  union { float f; unsigned u; } a; a.f = f;
  unsigned r = a.u + 0x7fffu + ((a.u >> 16) & 1u);
  return (unsigned short)(r >> 16);
}
__device__ __forceinline__ float bf2f(unsigned short s) {
  union { float f; unsigned u; } a; a.u = ((unsigned)s) << 16;
  return a.f;
}

// -------- weight prep: fp32 [K,N] -> bf16 transposed [N,K] (exact) ----------
struct PrepArgsV6 { const float* in[6]; unsigned short* out[6]; };

__global__ __launch_bounds__(256) void v6_prep_weights(PrepArgsV6 p) {
  const int sz[6]  = {65536, 65536, 262144, 131072, 32768, 8192};
  const int lgK[6] = {8, 8, 9, 9, 8, 7};
  const int Nn[6]  = {256, 256, 512, 256, 128, 64};
  int local = blockIdx.x * 256 + threadIdx.x;
  for (int i = 0; i < 6; ++i) {
    if (local < sz[i]) {
      int n = local >> lgK[i];
      int k = local & ((1 << lgK[i]) - 1);
      p.out[i][local] = f2bf(p.in[i][k * Nn[i] + n]);
      return;
    }
    local -= sz[i];
  }
}

// -------- per-graph mean + layer1 (3 -> 256) fp32, split-bf16 out -----------
__global__ __launch_bounds__(256) void v6_mean_l1(
    const float* __restrict__ x1, const float* __restrict__ x2,
    const float* __restrict__ W1, const float* __restrict__ b1,
    unsigned short* __restrict__ hhi, unsigned short* __restrict__ hlo) {
  int r = blockIdx.x;            // 0..24999, r = 2*g + side
  int c = threadIdx.x;           // 0..255
  int g = r >> 1;
  const float* x = (r & 1) ? x2 : x1;
  __shared__ float xs[12];
  if (c < 12) xs[c] = x[g * 12 + c];
  __syncthreads();
  float m0 = 0.25f * (xs[0] + xs[3] + xs[6] + xs[9]);
  float m1 = 0.25f * (xs[1] + xs[4] + xs[7] + xs[10]);
  float m2 = 0.25f * (xs[2] + xs[5] + xs[8] + xs[11]);
  float v = m0 * W1[c] + m1 * W1[256 + c] + m2 * W1[512 + c] + b1[c];
  v = fmaxf(v, 0.0f);
  unsigned short hi = f2bf(v);
  unsigned short lo = f2bf(v - bf2f(hi));
  hhi[r * 256 + c] = hi;
  hlo[r * 256 + c] = lo;
}

// -------- split-A bf16 MFMA GEMM: C = act(A@B + bias) -----------------------
// A as Ahi/Alo bf16 [M,K]; B as Bt bf16 [N,K] (transposed, exact bf16).
// mode 0: relu, write split bf16 Chi/Clo. mode 1: sigmoid, write fp32 Cout.
#define BM 128
#define BN 128
#define BK 32
#define LDA 40   // padded LDS row stride (shorts)

__global__ __launch_bounds__(256) void v6_gemm(
    const unsigned short* __restrict__ Ahi, const unsigned short* __restrict__ Alo,
    const unsigned short* __restrict__ Bt, const float* __restrict__ bias,
    unsigned short* __restrict__ Chi, unsigned short* __restrict__ Clo,
    float* __restrict__ Cout,
    int M, int N, int K, int mode) {
  __shared__ __align__(16) short sAh[BM][LDA];
  __shared__ __align__(16) short sAl[BM][LDA];
  __shared__ __align__(16) short sB[BN][LDA];

  int tid = threadIdx.x;
  int row0 = blockIdx.x * BM, col0 = blockIdx.y * BN;
  int wave = tid >> 6, lane = tid & 63;
  int wm = wave & 1, wn = wave >> 1;
  int quad = lane >> 4, lr = lane & 15;

  floatx4 acc[4][4];
  for (int i = 0; i < 4; ++i)
    for (int j = 0; j < 4; ++j)
      acc[i][j] = (floatx4){0.f, 0.f, 0.f, 0.f};

  int sr = tid >> 2;          // 0..63
  int sk = (tid & 3) * 8;     // 0,8,16,24

  for (int k0 = 0; k0 < K; k0 += BK) {
    __syncthreads();
    for (int h = 0; h < 2; ++h) {
      int r = sr + h * 64;
      int m = row0 + r;
      short8 vah = {0,0,0,0,0,0,0,0};
      short8 val = {0,0,0,0,0,0,0,0};
      short8 vbh = {0,0,0,0,0,0,0,0};
      if (m < M) {
        vah = *(const short8*)(Ahi + (size_t)m * K + k0 + sk);
        val = *(const short8*)(Alo + (size_t)m * K + k0 + sk);
      }
      int n = col0 + r;
      if (n < N) vbh = *(const short8*)(Bt + (size_t)n * K + k0 + sk);
      *(short8*)(&sAh[r][sk]) = vah;
      *(short8*)(&sAl[r][sk]) = val;
      *(short8*)(&sB[r][sk])  = vbh;
    }
    __syncthreads();

    short8 ah[4], al[4], bb[4];
#pragma unroll
    for (int t = 0; t < 4; ++t) {
      int ar = wm * 64 + t * 16 + lr;
      ah[t] = *(const short8*)(&sAh[ar][quad * 8]);
      al[t] = *(const short8*)(&sAl[ar][quad * 8]);
      int br = wn * 64 + t * 16 + lr;
      bb[t] = *(const short8*)(&sB[br][quad * 8]);
    }
#pragma unroll
    for (int tm = 0; tm < 4; ++tm)
#pragma unroll
      for (int tn = 0; tn < 4; ++tn) {
        acc[tm][tn] = __builtin_amdgcn_mfma_f32_16x16x32_bf16(ah[tm], bb[tn], acc[tm][tn], 0, 0, 0);
        acc[tm][tn] = __builtin_amdgcn_mfma_f32_16x16x32_bf16(al[tm], bb[tn], acc[tm][tn], 0, 0, 0);
      }
  }

  // epilogue: C row = quad*4 + reg, col = lane&15 (m89/m91-verified layout)
#pragma unroll
  for (int tm = 0; tm < 4; ++tm) {
#pragma unroll
    for (int tn = 0; tn < 4; ++tn) {
      int n = col0 + wn * 64 + tn * 16 + lr;
      if (n >= N) continue;
      float bv = bias[n];
#pragma unroll
      for (int reg = 0; reg < 4; ++reg) {
        int m = row0 + wm * 64 + tm * 16 + quad * 4 + reg;
        if (m >= M) continue;
        float v = acc[tm][tn][reg] + bv;
        if (mode == 0) {
          v = fmaxf(v, 0.0f);
          unsigned short hi = f2bf(v);
          unsigned short lo = f2bf(v - bf2f(hi));
          Chi[(size_t)m * N + n] = hi;
          Clo[(size_t)m * N + n] = lo;
        } else {
          Cout[(size_t)m * N + n] = 1.0f / (1.0f + expf(-v));   // fp32 output
        }
      }
    }
  }
}

extern "C" void kernel_launch(void* const* d_in, const int* in_sizes, int n_in,
                              void* d_out, int out_size, void* d_ws, size_t ws_size,
                              hipStream_t stream) {
  const float* x1  = (const float*)d_in[0];
  const float* x2  = (const float*)d_in[3];
  const float* W1  = (const float*)d_in[6];
  const float* b1  = (const float*)d_in[7];
  const float* W2  = (const float*)d_in[8];
  const float* b2  = (const float*)d_in[9];
  const float* W3  = (const float*)d_in[10];
  const float* b3  = (const float*)d_in[11];
  const float* Wl1 = (const float*)d_in[12];
  const float* bl1 = (const float*)d_in[13];
  const float* Wl2 = (const float*)d_in[14];
  const float* bl2 = (const float*)d_in[15];
  const float* Wl3 = (const float*)d_in[16];
  const float* bl3 = (const float*)d_in[17];
  const float* Wl4 = (const float*)d_in[18];
  const float* bl4 = (const float*)d_in[19];

  char* ws = (char*)d_ws;
  const size_t ACT = 6400000;   // max activation elements (25000*256)
  unsigned short* buf0hi = (unsigned short*)ws;   // [0, 12.8M)
  unsigned short* buf0lo = buf0hi + ACT;          // [12.8M, 25.6M)
  unsigned short* buf1hi = buf0lo + ACT;          // [25.6M, 38.4M)
  unsigned short* buf1lo = buf1hi + ACT;          // [38.4M, 51.2M)
  unsigned short* wt     = buf1lo + ACT;          // [51.2M, +1.13M)
  unsigned short* W2t  = wt;
  unsigned short* W3t  = W2t + 65536;
  unsigned short* Wl1t = W3t + 65536;
  unsigned short* Wl2t = Wl1t + 262144;
  unsigned short* Wl3t = Wl2t + 131072;
  unsigned short* Wl4t = Wl3t + 32768;

  PrepArgsV6 pa;
  pa.in[0] = W2;  pa.out[0] = W2t;
  pa.in[1] = W3;  pa.out[1] = W3t;
  pa.in[2] = Wl1; pa.out[2] = Wl1t;
  pa.in[3] = Wl2; pa.out[3] = Wl2t;
  pa.in[4] = Wl3; pa.out[4] = Wl3t;
  pa.in[5] = Wl4; pa.out[5] = Wl4t;

  dim3 blk(256);
  v6_prep_weights<<<dim3(2208), blk, 0, stream>>>(pa);
  v6_mean_l1<<<dim3(25000), blk, 0, stream>>>(x1, x2, W1, b1, buf0hi, buf0lo);

  // encode L2, L3 over batch 25000 (rows r = 2g+side)
  v6_gemm<<<dim3(196, 2), blk, 0, stream>>>(buf0hi, buf0lo, W2t, b2,
                                            buf1hi, buf1lo, nullptr, 25000, 256, 256, 0);
  v6_gemm<<<dim3(196, 2), blk, 0, stream>>>(buf1hi, buf1lo, W3t, b3,
                                            buf0hi, buf0lo, nullptr, 25000, 256, 256, 0);
  // head: view [25000,256] as [12500,512] (concat is free)
  v6_gemm<<<dim3(98, 4), blk, 0, stream>>>(buf0hi, buf0lo, Wl1t, bl1,
                                           buf1hi, buf1lo, nullptr, 12500, 512, 512, 0);
  v6_gemm<<<dim3(98, 2), blk, 0, stream>>>(buf1hi, buf1lo, Wl2t, bl2,
                                           buf0hi, buf0lo, nullptr, 12500, 256, 512, 0);
  v6_gemm<<<dim3(98, 1), blk, 0, stream>>>(buf0hi, buf0lo, Wl3t, bl3,
                                           buf1hi, buf1lo, nullptr, 12500, 128, 256, 0);
  v6_gemm<<<dim3(98, 1), blk, 0, stream>>>(buf1hi, buf1lo, Wl4t, bl4,
                                           nullptr, nullptr, (float*)d_out,
                                           12500, 64, 128, 1);
}

// Round 7
// 226.172 us; speedup vs baseline: 1.2451x; 1.2451x over previous
//
#include <hip/hip_runtime.h>

// GraphPairClassifier v7: single megakernel MLP.
//   GCN on all-edges tetrahedra collapses to: mean(4 nodes) -> L1(3->256) ->
//   L2 -> L3 (shared encoder, batch 25000 side-rows) -> concat (free via
//   r=2g+side) -> H1..H4 head on 12500 pair-rows.
//   Every pair-row is independent => one kernel, activations LDS-resident,
//   weights streamed from L2/L3 in MFMA-fragment order (coalesced).
// Dtypes: device inputs FP32 (bf16-quantized values => f2bf exact); out FP32.
// Precision: activations as hi+lo bf16 pairs, 2 MFMAs/tile (validated R6,
//   absmax 3.9e-3).

typedef short short8 __attribute__((ext_vector_type(8)));
typedef float floatx4 __attribute__((ext_vector_type(4)));

__device__ __forceinline__ unsigned short f2bf(float f) {
  union { float f; unsigned u; } a; a.f = f;
  unsigned r = a.u + 0x7fffu + ((a.u >> 16) & 1u);
  return (unsigned short)(r >> 16);
}
__device__ __forceinline__ float bf2f(unsigned short s) {
  union { float f; unsigned u; } a; a.u = ((unsigned)s) << 16;
  return a.f;
}

// -------- weight prep: fp32 [K,N] row-major -> bf16 MFMA-fragment order -----
// dst elem for (k,n): kb=k>>5, quad=(k>>3)&3, j=k&7, nt=n>>4, l16=n&15,
//   lane=quad*16+l16, off = ((kb*(N/16)+nt)*64+lane)*8 + j.
struct PrepArgsV7 { const float* in[6]; };

__global__ __launch_bounds__(256) void v7_prep(PrepArgsV7 p, unsigned short* Bf) {
  const int sz[6]  = {65536, 65536, 262144, 131072, 32768, 8192};
  const int lgN[6] = {8, 8, 9, 8, 7, 6};
  const int off[6] = {0, 65536, 131072, 393216, 524288, 557056};
  int e = blockIdx.x * 256 + threadIdx.x;
  for (int i = 0; i < 6; ++i) {
    if (e < sz[i]) {
      int N = 1 << lgN[i];
      int k = e >> lgN[i];
      int n = e & (N - 1);
      float w = p.in[i][e];                 // e == k*N + n (row-major)
      int kb = k >> 5, quad = (k >> 3) & 3, j = k & 7;
      int nt = n >> 4, l16 = n & 15;
      int lane = quad * 16 + l16;
      int dst = ((kb * (N >> 4) + nt) * 64 + lane) * 8 + j;
      Bf[off[i] + dst] = f2bf(w);
      return;
    }
    e -= sz[i];
  }
}

// -------- generic in-LDS layer ----------------------------------------------
// MT m-tiles (16 rows each), NT n-tiles per wave (4 waves cover N = NT*64),
// KB k-steps of 32. ENC_IN: A rows stride 264 (encode, 32 rows); else head
// layout rows stride 520 (16 pair rows).
// OUT_MODE 0: relu -> encode layout; 1: relu -> head layout from encode rows
// (r=2p+s); 2: relu -> head layout; 3: sigmoid -> global fp32.
template<int MT, int NT, int KB, bool ENC_IN, int OUT_MODE>
__device__ __forceinline__ void layer(
    const unsigned short* __restrict__ Bf, const float* __restrict__ bias,
    unsigned short* sHi, unsigned short* sLo,
    float* __restrict__ outg, int pair0, int wave, int lane) {
  const int quad = lane >> 4, lr = lane & 15;
  const int n0 = wave * (NT * 16);

  floatx4 acc[MT][NT];
#pragma unroll
  for (int mt = 0; mt < MT; ++mt)
#pragma unroll
    for (int nt = 0; nt < NT; ++nt)
      acc[mt][nt] = (floatx4){0.f, 0.f, 0.f, 0.f};

  for (int kb = 0; kb < KB; ++kb) {
    short8 ah[MT], al[MT];
#pragma unroll
    for (int mt = 0; mt < MT; ++mt) {
      int addr = (ENC_IN ? (mt * 16 + lr) * 264 : lr * 520) + kb * 32 + quad * 8;
      ah[mt] = *(const short8*)(sHi + addr);
      al[mt] = *(const short8*)(sLo + addr);
    }
#pragma unroll
    for (int nt = 0; nt < NT; ++nt) {
      short8 b = *(const short8*)(Bf + (size_t)((kb * (NT * 4) + wave * NT + nt) * 64 + lane) * 8);
#pragma unroll
      for (int mt = 0; mt < MT; ++mt) {
        acc[mt][nt] = __builtin_amdgcn_mfma_f32_16x16x32_bf16(ah[mt], b, acc[mt][nt], 0, 0, 0);
        acc[mt][nt] = __builtin_amdgcn_mfma_f32_16x16x32_bf16(al[mt], b, acc[mt][nt], 0, 0, 0);
      }
    }
  }

  __syncthreads();   // all waves finished reading A; safe to overwrite in place

#pragma unroll
  for (int nt = 0; nt < NT; ++nt) {
    int c = n0 + nt * 16 + lr;
    float bv = bias[c];
#pragma unroll
    for (int mt = 0; mt < MT; ++mt) {
#pragma unroll
      for (int reg = 0; reg < 4; ++reg) {
        int r = mt * 16 + quad * 4 + reg;
        float v = acc[mt][nt][reg] + bv;
        if (OUT_MODE <= 2) {
          v = fmaxf(v, 0.f);
          unsigned short h = f2bf(v);
          unsigned short l = f2bf(v - bf2f(h));
          int a;
          if (OUT_MODE == 0)      a = r * 264 + c;                        // encode
          else if (OUT_MODE == 1) a = (r >> 1) * 520 + (r & 1) * 256 + c; // -> head
          else                    a = r * 520 + c;                        // head
          sHi[a] = h; sLo[a] = l;
        } else {
          int p = pair0 + r;
          if (p < 12500) outg[(size_t)p * 64 + c] = 1.0f / (1.0f + expf(-v));
        }
      }
    }
  }
  __syncthreads();
}

// -------- megakernel --------------------------------------------------------
__global__ __launch_bounds__(256) void v7_mega(
    const float* __restrict__ x1, const float* __restrict__ x2,
    const float* __restrict__ W1, const float* __restrict__ b1,
    const unsigned short* __restrict__ Bf,
    const float* __restrict__ b2, const float* __restrict__ b3,
    const float* __restrict__ bl1, const float* __restrict__ bl2,
    const float* __restrict__ bl3, const float* __restrict__ bl4,
    float* __restrict__ outg) {
  __shared__ unsigned short sHi[8448];   // encode: [32][264]; head: [16][520]
  __shared__ unsigned short sLo[8448];
  __shared__ float sM[32][3];

  int tid = threadIdx.x;
  int wave = tid >> 6, lane = tid & 63;
  int pair0 = blockIdx.x * 16;

  // Phase 0: per-side-row mean of 4 node coords
  if (tid < 32) {
    int r = tid;
    int g = pair0 + (r >> 1);
    const float* xp = (r & 1) ? x2 : x1;
    float a0 = 0.f, a1 = 0.f, a2 = 0.f;
    if (g < 12500) {
      const float* q = xp + (size_t)g * 12;
      a0 = 0.25f * (q[0] + q[3] + q[6] + q[9]);
      a1 = 0.25f * (q[1] + q[4] + q[7] + q[10]);
      a2 = 0.25f * (q[2] + q[5] + q[8] + q[11]);
    }
    sM[r][0] = a0; sM[r][1] = a1; sM[r][2] = a2;
  }
  __syncthreads();

  // Phase 1: L1 (3 -> 256), fp32 VALU, split-bf16 into LDS (encode layout)
  {
    int c = tid;  // 0..255
    float w0 = W1[c], w1 = W1[256 + c], w2 = W1[512 + c], bb = b1[c];
#pragma unroll 4
    for (int r = 0; r < 32; ++r) {
      float v = fmaxf(sM[r][0] * w0 + sM[r][1] * w1 + sM[r][2] * w2 + bb, 0.f);
      unsigned short h = f2bf(v);
      sHi[r * 264 + c] = h;
      sLo[r * 264 + c] = f2bf(v - bf2f(h));
    }
  }
  __syncthreads();

  // L2: [32x256]@[256x256] relu, encode->encode
  layer<2, 4, 8, true, 0>(Bf + 0,      b2,  sHi, sLo, nullptr, pair0, wave, lane);
  // L3: [32x256]@[256x256] relu, encode->head (concat)
  layer<2, 4, 8, true, 1>(Bf + 65536,  b3,  sHi, sLo, nullptr, pair0, wave, lane);
  // H1: [16x512]@[512x512] relu
  layer<1, 8, 16, false, 2>(Bf + 131072, bl1, sHi, sLo, nullptr, pair0, wave, lane);
  // H2: [16x512]@[512x256] relu
  layer<1, 4, 16, false, 2>(Bf + 393216, bl2, sHi, sLo, nullptr, pair0, wave, lane);
  // H3: [16x256]@[256x128] relu
  layer<1, 2, 8, false, 2>(Bf + 524288, bl3, sHi, sLo, nullptr, pair0, wave, lane);
  // H4: [16x128]@[128x64] sigmoid -> global
  layer<1, 1, 4, false, 3>(Bf + 557056, bl4, sHi, sLo, outg,    pair0, wave, lane);
}

extern "C" void kernel_launch(void* const* d_in, const int* in_sizes, int n_in,
                              void* d_out, int out_size, void* d_ws, size_t ws_size,
                              hipStream_t stream) {
  const float* x1  = (const float*)d_in[0];
  const float* x2  = (const float*)d_in[3];
  const float* W1  = (const float*)d_in[6];
  const float* b1  = (const float*)d_in[7];
  const float* W2  = (const float*)d_in[8];
  const float* b2  = (const float*)d_in[9];
  const float* W3  = (const float*)d_in[10];
  const float* b3  = (const float*)d_in[11];
  const float* Wl1 = (const float*)d_in[12];
  const float* bl1 = (const float*)d_in[13];
  const float* Wl2 = (const float*)d_in[14];
  const float* bl2 = (const float*)d_in[15];
  const float* Wl3 = (const float*)d_in[16];
  const float* bl3 = (const float*)d_in[17];
  const float* Wl4 = (const float*)d_in[18];
  const float* bl4 = (const float*)d_in[19];

  unsigned short* Bf = (unsigned short*)d_ws;   // 565248 shorts = 1.13 MB

  PrepArgsV7 pa;
  pa.in[0] = W2;  pa.in[1] = W3;  pa.in[2] = Wl1;
  pa.in[3] = Wl2; pa.in[4] = Wl3; pa.in[5] = Wl4;

  v7_prep<<<dim3(2208), dim3(256), 0, stream>>>(pa, Bf);
  v7_mega<<<dim3(782), dim3(256), 0, stream>>>(x1, x2, W1, b1, Bf,
                                               b2, b3, bl1, bl2, bl3, bl4,
                                               (float*)d_out);
}

// Round 8
// 141.040 us; speedup vs baseline: 1.9966x; 1.6036x over previous
//
#include <hip/hip_runtime.h>

// GraphPairClassifier v8: megakernel MLP + register double-buffered B-prefetch.
//   GCN on all-edge tetrahedra collapses to: mean(4 nodes) -> L1(3->256) ->
//   L2 -> L3 (batch 25000 side rows) -> concat (free, r=2g+side) -> H1..H4
//   (12500 pair rows). Activations LDS-resident; weights streamed from L2 in
//   MFMA-fragment order; B-frags prefetched one k-step ahead (ping-pong regs).
// Dtypes: device inputs FP32 (bf16-quantized values); output FP32.
// Precision: activations as hi+lo bf16 pairs, 2 MFMAs/tile (absmax 3.9e-3, R6/R7).

typedef short short8 __attribute__((ext_vector_type(8)));
typedef float floatx4 __attribute__((ext_vector_type(4)));

__device__ __forceinline__ unsigned short f2bf(float f) {
  union { float f; unsigned u; } a; a.f = f;
  unsigned r = a.u + 0x7fffu + ((a.u >> 16) & 1u);
  return (unsigned short)(r >> 16);
}
__device__ __forceinline__ float bf2f(unsigned short s) {
  union { float f; unsigned u; } a; a.u = ((unsigned)s) << 16;
  return a.f;
}

// -------- weight prep: fp32 [K,N] row-major -> bf16 MFMA-fragment order -----
// dst for (k,n): kb=k>>5, quad=(k>>3)&3, j=k&7, nt=n>>4, l16=n&15,
//   lane=quad*16+l16, off = ((kb*(N/16)+nt)*64+lane)*8 + j.
struct PrepArgsV8 { const float* in[6]; };

__global__ __launch_bounds__(256) void v8_prep(PrepArgsV8 p, unsigned short* Bf) {
  const int sz[6]  = {65536, 65536, 262144, 131072, 32768, 8192};
  const int lgN[6] = {8, 8, 9, 8, 7, 6};
  const int off[6] = {0, 65536, 131072, 393216, 524288, 557056};
  int e = blockIdx.x * 256 + threadIdx.x;
  for (int i = 0; i < 6; ++i) {
    if (e < sz[i]) {
      int N = 1 << lgN[i];
      int k = e >> lgN[i];
      int n = e & (N - 1);
      float w = p.in[i][e];
      int kb = k >> 5, quad = (k >> 3) & 3, j = k & 7;
      int nt = n >> 4, l16 = n & 15;
      int lane = quad * 16 + l16;
      int dst = ((kb * (N >> 4) + nt) * 64 + lane) * 8 + j;
      Bf[off[i] + dst] = f2bf(w);
      return;
    }
    e -= sz[i];
  }
}

// -------- generic in-LDS layer with B register double-buffer ----------------
// MT m-tiles (16 rows), NT n-tiles per wave (4 waves cover N=NT*64), KB k-steps
// of 32. ENC_IN: A rows stride 264 (encode, 32 rows); else head stride 520.
// OUT_MODE 0: relu->encode; 1: relu->head (from encode rows, r=2p+s);
//          2: relu->head; 3: sigmoid->global fp32.
template<int MT, int NT, int KB, bool ENC_IN, int OUT_MODE>
__device__ __forceinline__ void layer(
    const unsigned short* __restrict__ Bf, const float* __restrict__ bias,
    unsigned short* sHi, unsigned short* sLo,
    float* __restrict__ outg, int pair0, int wave, int lane) {
  const int quad = lane >> 4, lr = lane & 15;
  const int n0 = wave * (NT * 16);
  const unsigned short* bp = Bf + ((size_t)(wave * NT) * 64 + lane) * 8;

  floatx4 acc[MT][NT];
#pragma unroll
  for (int mt = 0; mt < MT; ++mt)
#pragma unroll
    for (int nt = 0; nt < NT; ++nt)
      acc[mt][nt] = (floatx4){0.f, 0.f, 0.f, 0.f};

  short8 bbuf[2][NT];
#pragma unroll
  for (int nt = 0; nt < NT; ++nt)
    bbuf[0][nt] = *(const short8*)(bp + nt * 512);

#pragma unroll 2
  for (int kb = 0; kb < KB; ++kb) {
    const int cur = kb & 1, nxt = cur ^ 1;
    if (kb + 1 < KB) {
#pragma unroll
      for (int nt = 0; nt < NT; ++nt)
        bbuf[nxt][nt] = *(const short8*)(bp + (size_t)(kb + 1) * (NT * 2048) + nt * 512);
    }
    short8 ah[MT], al[MT];
#pragma unroll
    for (int mt = 0; mt < MT; ++mt) {
      int addr = (ENC_IN ? (mt * 16 + lr) * 264 : lr * 520) + kb * 32 + quad * 8;
      ah[mt] = *(const short8*)(sHi + addr);
      al[mt] = *(const short8*)(sLo + addr);
    }
#pragma unroll
    for (int nt = 0; nt < NT; ++nt)
#pragma unroll
      for (int mt = 0; mt < MT; ++mt) {
        acc[mt][nt] = __builtin_amdgcn_mfma_f32_16x16x32_bf16(ah[mt], bbuf[cur][nt], acc[mt][nt], 0, 0, 0);
        acc[mt][nt] = __builtin_amdgcn_mfma_f32_16x16x32_bf16(al[mt], bbuf[cur][nt], acc[mt][nt], 0, 0, 0);
      }
  }

  __syncthreads();   // all waves done reading A; safe to overwrite in place

#pragma unroll
  for (int nt = 0; nt < NT; ++nt) {
    int c = n0 + nt * 16 + lr;
    float bv = bias[c];
#pragma unroll
    for (int mt = 0; mt < MT; ++mt) {
#pragma unroll
      for (int reg = 0; reg < 4; ++reg) {
        int r = mt * 16 + quad * 4 + reg;
        float v = acc[mt][nt][reg] + bv;
        if (OUT_MODE <= 2) {
          v = fmaxf(v, 0.f);
          unsigned short h = f2bf(v);
          unsigned short l = f2bf(v - bf2f(h));
          int a;
          if (OUT_MODE == 0)      a = r * 264 + c;
          else if (OUT_MODE == 1) a = (r >> 1) * 520 + (r & 1) * 256 + c;
          else                    a = r * 520 + c;
          sHi[a] = h; sLo[a] = l;
        } else {
          int p = pair0 + r;
          if (p < 12500) outg[(size_t)p * 64 + c] = 1.0f / (1.0f + expf(-v));
        }
      }
    }
  }
  __syncthreads();
}

// -------- megakernel --------------------------------------------------------
__global__ __launch_bounds__(256, 3) void v8_mega(
    const float* __restrict__ x1, const float* __restrict__ x2,
    const float* __restrict__ W1, const float* __restrict__ b1,
    const unsigned short* __restrict__ Bf,
    const float* __restrict__ b2, const float* __restrict__ b3,
    const float* __restrict__ bl1, const float* __restrict__ bl2,
    const float* __restrict__ bl3, const float* __restrict__ bl4,
    float* __restrict__ outg) {
  __shared__ unsigned short sHi[8448];   // encode: [32][264]; head: [16][520]
  __shared__ unsigned short sLo[8448];
  __shared__ float sM[32][3];

  int tid = threadIdx.x;
  int wave = tid >> 6, lane = tid & 63;
  int pair0 = blockIdx.x * 16;

  // Phase 0: per-side-row mean of the 4 node coords
  if (tid < 32) {
    int r = tid;
    int g = pair0 + (r >> 1);
    const float* xp = (r & 1) ? x2 : x1;
    float a0 = 0.f, a1 = 0.f, a2 = 0.f;
    if (g < 12500) {
      const float* q = xp + (size_t)g * 12;
      a0 = 0.25f * (q[0] + q[3] + q[6] + q[9]);
      a1 = 0.25f * (q[1] + q[4] + q[7] + q[10]);
      a2 = 0.25f * (q[2] + q[5] + q[8] + q[11]);
    }
    sM[r][0] = a0; sM[r][1] = a1; sM[r][2] = a2;
  }
  __syncthreads();

  // Phase 1: L1 (3 -> 256), fp32 VALU, split-bf16 into LDS (encode layout)
  {
    int c = tid;
    float w0 = W1[c], w1 = W1[256 + c], w2 = W1[512 + c], bb = b1[c];
#pragma unroll 4
    for (int r = 0; r < 32; ++r) {
      float v = fmaxf(sM[r][0] * w0 + sM[r][1] * w1 + sM[r][2] * w2 + bb, 0.f);
      unsigned short h = f2bf(v);
      sHi[r * 264 + c] = h;
      sLo[r * 264 + c] = f2bf(v - bf2f(h));
    }
  }
  __syncthreads();

  // L2: [32x256]@[256x256] relu, encode->encode
  layer<2, 4, 8, true, 0>(Bf + 0,      b2,  sHi, sLo, nullptr, pair0, wave, lane);
  // L3: [32x256]@[256x256] relu, encode->head (concat)
  layer<2, 4, 8, true, 1>(Bf + 65536,  b3,  sHi, sLo, nullptr, pair0, wave, lane);
  // H1: [16x512]@[512x512] relu
  layer<1, 8, 16, false, 2>(Bf + 131072, bl1, sHi, sLo, nullptr, pair0, wave, lane);
  // H2: [16x512]@[512x256] relu
  layer<1, 4, 16, false, 2>(Bf + 393216, bl2, sHi, sLo, nullptr, pair0, wave, lane);
  // H3: [16x256]@[256x128] relu
  layer<1, 2, 8, false, 2>(Bf + 524288, bl3, sHi, sLo, nullptr, pair0, wave, lane);
  // H4: [16x128]@[128x64] sigmoid -> global
  layer<1, 1, 4, false, 3>(Bf + 557056, bl4, sHi, sLo, outg,    pair0, wave, lane);
}

extern "C" void kernel_launch(void* const* d_in, const int* in_sizes, int n_in,
                              void* d_out, int out_size, void* d_ws, size_t ws_size,
                              hipStream_t stream) {
  const float* x1  = (const float*)d_in[0];
  const float* x2  = (const float*)d_in[3];
  const float* W1  = (const float*)d_in[6];
  const float* b1  = (const float*)d_in[7];
  const float* W2  = (const float*)d_in[8];
  const float* b2  = (const float*)d_in[9];
  const float* W3  = (const float*)d_in[10];
  const float* b3  = (const float*)d_in[11];
  const float* Wl1 = (const float*)d_in[12];
  const float* bl1 = (const float*)d_in[13];
  const float* Wl2 = (const float*)d_in[14];
  const float* bl2 = (const float*)d_in[15];
  const float* Wl3 = (const float*)d_in[16];
  const float* bl3 = (const float*)d_in[17];
  const float* Wl4 = (const float*)d_in[18];
  const float* bl4 = (const float*)d_in[19];

  unsigned short* Bf = (unsigned short*)d_ws;   // 565248 shorts = 1.13 MB

  PrepArgsV8 pa;
  pa.in[0] = W2;  pa.in[1] = W3;  pa.in[2] = Wl1;
  pa.in[3] = Wl2; pa.in[4] = Wl3; pa.in[5] = Wl4;

  v8_prep<<<dim3(2208), dim3(256), 0, stream>>>(pa, Bf);
  v8_mega<<<dim3(782), dim3(256), 0, stream>>>(x1, x2, W1, b1, Bf,
                                               b2, b3, bl1, bl2, bl3, bl4,
                                               (float*)d_out);
}

// Round 9
// 136.710 us; speedup vs baseline: 2.0599x; 1.0317x over previous
//
#include <hip/hip_runtime.h>

// GraphPairClassifier v9: megakernel, 32 pairs/block (2x arithmetic intensity
//   vs v8: every block still streams all 1.13 MB of weights, but runs 2x the
//   MFMAs per fragment; total L2 weight traffic halves to 441 MB).
//   GCN on all-edge tetrahedra collapses to: mean(4) -> L1(3->256) -> L2 ->
//   L3 -> concat(free, r=2g+side) -> H1..H4. Activations LDS-resident
//   (~67 KB, gfx950 LDS=160KB => 2 blocks/CU); weights in MFMA-fragment
//   order streamed from L2 with register ping-pong prefetch.
// Dtypes: device inputs FP32 (bf16-quantized values); output FP32.
// Precision: activations as hi+lo bf16 pairs, 2 MFMAs/tile (absmax 3.9e-3,
//   stable R6-R8).

typedef short short8 __attribute__((ext_vector_type(8)));
typedef float floatx4 __attribute__((ext_vector_type(4)));

__device__ __forceinline__ unsigned short f2bf(float f) {
  union { float f; unsigned u; } a; a.f = f;
  unsigned r = a.u + 0x7fffu + ((a.u >> 16) & 1u);
  return (unsigned short)(r >> 16);
}
__device__ __forceinline__ float bf2f(unsigned short s) {
  union { float f; unsigned u; } a; a.u = ((unsigned)s) << 16;
  return a.f;
}

// -------- weight prep: fp32 [K,N] row-major -> bf16 MFMA-fragment order -----
// dst for (k,n): kb=k>>5, quad=(k>>3)&3, j=k&7, nt=n>>4, l16=n&15,
//   lane=quad*16+l16, off = ((kb*(N/16)+nt)*64+lane)*8 + j.
struct PrepArgsV9 { const float* in[6]; };

__global__ __launch_bounds__(256) void v9_prep(PrepArgsV9 p, unsigned short* Bf) {
  const int sz[6]  = {65536, 65536, 262144, 131072, 32768, 8192};
  const int lgN[6] = {8, 8, 9, 8, 7, 6};
  const int off[6] = {0, 65536, 131072, 393216, 524288, 557056};
  int e = blockIdx.x * 256 + threadIdx.x;
  for (int i = 0; i < 6; ++i) {
    if (e < sz[i]) {
      int N = 1 << lgN[i];
      int k = e >> lgN[i];
      int n = e & (N - 1);
      float w = p.in[i][e];
      int kb = k >> 5, quad = (k >> 3) & 3, j = k & 7;
      int nt = n >> 4, l16 = n & 15;
      int lane = quad * 16 + l16;
      int dst = ((kb * (N >> 4) + nt) * 64 + lane) * 8 + j;
      Bf[off[i] + dst] = f2bf(w);
      return;
    }
    e -= sz[i];
  }
}

// -------- generic in-LDS layer with B register double-buffer ----------------
// MT m-tiles (16 rows), NT n-tiles per wave (4 waves cover N=NT*64), KB
// k-steps of 32. ENC_IN: A stride 264 shorts (encode, 64 rows); else head
// stride 520 (32 pair rows).
// OUT_MODE 0: relu->encode; 1: relu->head (encode rows r=2p+s -> pair rows);
//          2: relu->head; 3: sigmoid->global fp32.
template<int MT, int NT, int KB, bool ENC_IN, int OUT_MODE>
__device__ __forceinline__ void layer(
    const unsigned short* __restrict__ Bf, const float* __restrict__ bias,
    unsigned short* sHi, unsigned short* sLo,
    float* __restrict__ outg, int pair0, int wave, int lane) {
  const int quad = lane >> 4, lr = lane & 15;
  const int n0 = wave * (NT * 16);
  const unsigned short* bp = Bf + ((size_t)(wave * NT) * 64 + lane) * 8;

  floatx4 acc[MT][NT];
#pragma unroll
  for (int mt = 0; mt < MT; ++mt)
#pragma unroll
    for (int nt = 0; nt < NT; ++nt)
      acc[mt][nt] = (floatx4){0.f, 0.f, 0.f, 0.f};

  short8 bbuf[2][NT];
#pragma unroll
  for (int nt = 0; nt < NT; ++nt)
    bbuf[0][nt] = *(const short8*)(bp + nt * 512);

#pragma unroll 2
  for (int kb = 0; kb < KB; ++kb) {
    const int cur = kb & 1, nxt = cur ^ 1;
    if (kb + 1 < KB) {
#pragma unroll
      for (int nt = 0; nt < NT; ++nt)
        bbuf[nxt][nt] = *(const short8*)(bp + (size_t)(kb + 1) * (NT * 2048) + nt * 512);
    }
    short8 ah[MT], al[MT];
#pragma unroll
    for (int mt = 0; mt < MT; ++mt) {
      int addr = (mt * 16 + lr) * (ENC_IN ? 264 : 520) + kb * 32 + quad * 8;
      ah[mt] = *(const short8*)(sHi + addr);
      al[mt] = *(const short8*)(sLo + addr);
    }
#pragma unroll
    for (int nt = 0; nt < NT; ++nt)
#pragma unroll
      for (int mt = 0; mt < MT; ++mt) {
        acc[mt][nt] = __builtin_amdgcn_mfma_f32_16x16x32_bf16(ah[mt], bbuf[cur][nt], acc[mt][nt], 0, 0, 0);
        acc[mt][nt] = __builtin_amdgcn_mfma_f32_16x16x32_bf16(al[mt], bbuf[cur][nt], acc[mt][nt], 0, 0, 0);
      }
  }

  __syncthreads();   // all waves done reading A; safe to overwrite in place

#pragma unroll
  for (int nt = 0; nt < NT; ++nt) {
    int c = n0 + nt * 16 + lr;
    float bv = bias[c];
#pragma unroll
    for (int mt = 0; mt < MT; ++mt) {
#pragma unroll
      for (int reg = 0; reg < 4; ++reg) {
        int r = mt * 16 + quad * 4 + reg;
        float v = acc[mt][nt][reg] + bv;
        if (OUT_MODE <= 2) {
          v = fmaxf(v, 0.f);
          unsigned short h = f2bf(v);
          unsigned short l = f2bf(v - bf2f(h));
          int a;
          if (OUT_MODE == 0)      a = r * 264 + c;                        // encode
          else if (OUT_MODE == 1) a = (r >> 1) * 520 + (r & 1) * 256 + c; // concat
          else                    a = r * 520 + c;                        // head
          sHi[a] = h; sLo[a] = l;
        } else {
          int p = pair0 + r;
          if (p < 12500) outg[(size_t)p * 64 + c] = 1.0f / (1.0f + expf(-v));
        }
      }
    }
  }
  __syncthreads();
}

// -------- megakernel: 32 pairs (64 side rows) per block ---------------------
__global__ __launch_bounds__(256, 2) void v9_mega(
    const float* __restrict__ x1, const float* __restrict__ x2,
    const float* __restrict__ W1, const float* __restrict__ b1,
    const unsigned short* __restrict__ Bf,
    const float* __restrict__ b2, const float* __restrict__ b3,
    const float* __restrict__ bl1, const float* __restrict__ bl2,
    const float* __restrict__ bl3, const float* __restrict__ bl4,
    float* __restrict__ outg) {
  __shared__ unsigned short sHi[16896];  // encode: [64][264]; head: [32][520]
  __shared__ unsigned short sLo[16896];
  __shared__ float sM[64][3];

  int tid = threadIdx.x;
  int wave = tid >> 6, lane = tid & 63;
  int pair0 = blockIdx.x * 32;

  // Phase 0: per-side-row mean of the 4 node coords (64 rows)
  if (tid < 64) {
    int r = tid;
    int g = pair0 + (r >> 1);
    const float* xp = (r & 1) ? x2 : x1;
    float a0 = 0.f, a1 = 0.f, a2 = 0.f;
    if (g < 12500) {
      const float* q = xp + (size_t)g * 12;
      a0 = 0.25f * (q[0] + q[3] + q[6] + q[9]);
      a1 = 0.25f * (q[1] + q[4] + q[7] + q[10]);
      a2 = 0.25f * (q[2] + q[5] + q[8] + q[11]);
    }
    sM[r][0] = a0; sM[r][1] = a1; sM[r][2] = a2;
  }
  __syncthreads();

  // Phase 1: L1 (3 -> 256), fp32 VALU, split-bf16 into LDS (encode layout)
  {
    int c = tid;
    float w0 = W1[c], w1 = W1[256 + c], w2 = W1[512 + c], bb = b1[c];
#pragma unroll 4
    for (int r = 0; r < 64; ++r) {
      float v = fmaxf(sM[r][0] * w0 + sM[r][1] * w1 + sM[r][2] * w2 + bb, 0.f);
      unsigned short h = f2bf(v);
      sHi[r * 264 + c] = h;
      sLo[r * 264 + c] = f2bf(v - bf2f(h));
    }
  }
  __syncthreads();

  // L2: [64x256]@[256x256] relu, encode->encode
  layer<4, 4, 8, true, 0>(Bf + 0,      b2,  sHi, sLo, nullptr, pair0, wave, lane);
  // L3: [64x256]@[256x256] relu, encode->head (concat)
  layer<4, 4, 8, true, 1>(Bf + 65536,  b3,  sHi, sLo, nullptr, pair0, wave, lane);
  // H1: [32x512]@[512x512] relu
  layer<2, 8, 16, false, 2>(Bf + 131072, bl1, sHi, sLo, nullptr, pair0, wave, lane);
  // H2: [32x512]@[512x256] relu
  layer<2, 4, 16, false, 2>(Bf + 393216, bl2, sHi, sLo, nullptr, pair0, wave, lane);
  // H3: [32x256]@[256x128] relu
  layer<2, 2, 8, false, 2>(Bf + 524288, bl3, sHi, sLo, nullptr, pair0, wave, lane);
  // H4: [32x128]@[128x64] sigmoid -> global
  layer<2, 1, 4, false, 3>(Bf + 557056, bl4, sHi, sLo, outg,    pair0, wave, lane);
}

extern "C" void kernel_launch(void* const* d_in, const int* in_sizes, int n_in,
                              void* d_out, int out_size, void* d_ws, size_t ws_size,
                              hipStream_t stream) {
  const float* x1  = (const float*)d_in[0];
  const float* x2  = (const float*)d_in[3];
  const float* W1  = (const float*)d_in[6];
  const float* b1  = (const float*)d_in[7];
  const float* W2  = (const float*)d_in[8];
  const float* b2  = (const float*)d_in[9];
  const float* W3  = (const float*)d_in[10];
  const float* b3  = (const float*)d_in[11];
  const float* Wl1 = (const float*)d_in[12];
  const float* bl1 = (const float*)d_in[13];
  const float* Wl2 = (const float*)d_in[14];
  const float* bl2 = (const float*)d_in[15];
  const float* Wl3 = (const float*)d_in[16];
  const float* bl3 = (const float*)d_in[17];
  const float* Wl4 = (const float*)d_in[18];
  const float* bl4 = (const float*)d_in[19];

  unsigned short* Bf = (unsigned short*)d_ws;   // 565248 shorts = 1.13 MB

  PrepArgsV9 pa;
  pa.in[0] = W2;  pa.in[1] = W3;  pa.in[2] = Wl1;
  pa.in[3] = Wl2; pa.in[4] = Wl3; pa.in[5] = Wl4;

  v9_prep<<<dim3(2208), dim3(256), 0, stream>>>(pa, Bf);
  v9_mega<<<dim3(391), dim3(256), 0, stream>>>(x1, x2, W1, b1, Bf,
                                               b2, b3, bl1, bl2, bl3, bl4,
                                               (float*)d_out);
}

// Round 10
// 128.658 us; speedup vs baseline: 2.1888x; 1.0626x over previous
//
#include <hip/hip_runtime.h>

// GraphPairClassifier v10: megakernel, single-plane FP16 activations.
//   R9 evidence: time invariant across block configs at ~28% MFMA + ~25% VALU
//   => bound by total issued instructions. Halve the stream: one fp16 MFMA
//   per tile instead of bf16 hi+lo pair. Weights are bf16-valued => fp16
//   conversion exact; only activations rounded (2^-11 rel, fp32 accumulate).
//   Structure: mean(4) -> L1(3->256) -> L2 -> L3 -> concat(free, r=2g+side)
//   -> H1..H4; activations LDS-resident; weights in MFMA-fragment order
//   streamed from L2 with register ping-pong prefetch. 32 pairs/block.
// Dtypes: device inputs FP32 (bf16-quantized values); output FP32.

typedef _Float16 half8 __attribute__((ext_vector_type(8)));
typedef float floatx4 __attribute__((ext_vector_type(4)));

// -------- weight prep: fp32 [K,N] row-major -> fp16 MFMA-fragment order -----
// dst for (k,n): kb=k>>5, quad=(k>>3)&3, j=k&7, nt=n>>4, l16=n&15,
//   lane=quad*16+l16, off = ((kb*(N/16)+nt)*64+lane)*8 + j.
struct PrepArgsV10 { const float* in[6]; };

__global__ __launch_bounds__(256) void v10_prep(PrepArgsV10 p, _Float16* Bf) {
  const int sz[6]  = {65536, 65536, 262144, 131072, 32768, 8192};
  const int lgN[6] = {8, 8, 9, 8, 7, 6};
  const int off[6] = {0, 65536, 131072, 393216, 524288, 557056};
  int e = blockIdx.x * 256 + threadIdx.x;
  for (int i = 0; i < 6; ++i) {
    if (e < sz[i]) {
      int N = 1 << lgN[i];
      int k = e >> lgN[i];
      int n = e & (N - 1);
      float w = p.in[i][e];
      int kb = k >> 5, quad = (k >> 3) & 3, j = k & 7;
      int nt = n >> 4, l16 = n & 15;
      int lane = quad * 16 + l16;
      int dst = ((kb * (N >> 4) + nt) * 64 + lane) * 8 + j;
      Bf[off[i] + dst] = (_Float16)w;   // exact: weights are bf16-valued
      return;
    }
    e -= sz[i];
  }
}

// -------- generic in-LDS layer with B register double-buffer ----------------
// MT m-tiles (16 rows), NT n-tiles per wave (4 waves cover N=NT*64), KB
// k-steps of 32. ENC_IN: A stride 264 halves (encode, 64 rows); else head
// stride 520 (32 pair rows).
// OUT_MODE 0: relu->encode; 1: relu->head (encode rows r=2p+s -> pair rows);
//          2: relu->head; 3: sigmoid->global fp32.
template<int MT, int NT, int KB, bool ENC_IN, int OUT_MODE>
__device__ __forceinline__ void layer(
    const _Float16* __restrict__ Bf, const float* __restrict__ bias,
    _Float16* sA, float* __restrict__ outg, int pair0, int wave, int lane) {
  const int quad = lane >> 4, lr = lane & 15;
  const int n0 = wave * (NT * 16);
  const _Float16* bp = Bf + ((size_t)(wave * NT) * 64 + lane) * 8;

  floatx4 acc[MT][NT];
#pragma unroll
  for (int mt = 0; mt < MT; ++mt)
#pragma unroll
    for (int nt = 0; nt < NT; ++nt)
      acc[mt][nt] = (floatx4){0.f, 0.f, 0.f, 0.f};

  half8 bbuf[2][NT];
#pragma unroll
  for (int nt = 0; nt < NT; ++nt)
    bbuf[0][nt] = *(const half8*)(bp + nt * 512);

#pragma unroll 2
  for (int kb = 0; kb < KB; ++kb) {
    const int cur = kb & 1, nxt = cur ^ 1;
    if (kb + 1 < KB) {
#pragma unroll
      for (int nt = 0; nt < NT; ++nt)
        bbuf[nxt][nt] = *(const half8*)(bp + (size_t)(kb + 1) * (NT * 2048) + nt * 512);
    }
    half8 av[MT];
#pragma unroll
    for (int mt = 0; mt < MT; ++mt) {
      int addr = (mt * 16 + lr) * (ENC_IN ? 264 : 520) + kb * 32 + quad * 8;
      av[mt] = *(const half8*)(sA + addr);
    }
#pragma unroll
    for (int nt = 0; nt < NT; ++nt)
#pragma unroll
      for (int mt = 0; mt < MT; ++mt)
        acc[mt][nt] = __builtin_amdgcn_mfma_f32_16x16x32_f16(av[mt], bbuf[cur][nt], acc[mt][nt], 0, 0, 0);
  }

  __syncthreads();   // all waves done reading A; safe to overwrite in place

#pragma unroll
  for (int nt = 0; nt < NT; ++nt) {
    int c = n0 + nt * 16 + lr;
    float bv = bias[c];
#pragma unroll
    for (int mt = 0; mt < MT; ++mt) {
#pragma unroll
      for (int reg = 0; reg < 4; ++reg) {
        int r = mt * 16 + quad * 4 + reg;
        float v = acc[mt][nt][reg] + bv;
        if (OUT_MODE <= 2) {
          v = fmaxf(v, 0.f);
          int a;
          if (OUT_MODE == 0)      a = r * 264 + c;                        // encode
          else if (OUT_MODE == 1) a = (r >> 1) * 520 + (r & 1) * 256 + c; // concat
          else                    a = r * 520 + c;                        // head
          sA[a] = (_Float16)v;
        } else {
          int p = pair0 + r;
          if (p < 12500) outg[(size_t)p * 64 + c] = 1.0f / (1.0f + expf(-v));
        }
      }
    }
  }
  __syncthreads();
}

// -------- megakernel: 32 pairs (64 side rows) per block ---------------------
__global__ __launch_bounds__(256) void v10_mega(
    const float* __restrict__ x1, const float* __restrict__ x2,
    const float* __restrict__ W1, const float* __restrict__ b1,
    const _Float16* __restrict__ Bf,
    const float* __restrict__ b2, const float* __restrict__ b3,
    const float* __restrict__ bl1, const float* __restrict__ bl2,
    const float* __restrict__ bl3, const float* __restrict__ bl4,
    float* __restrict__ outg) {
  __shared__ _Float16 sA[16896];   // encode: [64][264]; head: [32][520]
  __shared__ float sM[64][3];

  int tid = threadIdx.x;
  int wave = tid >> 6, lane = tid & 63;
  int pair0 = blockIdx.x * 32;

  // Phase 0: per-side-row mean of the 4 node coords (64 rows)
  if (tid < 64) {
    int r = tid;
    int g = pair0 + (r >> 1);
    const float* xp = (r & 1) ? x2 : x1;
    float a0 = 0.f, a1 = 0.f, a2 = 0.f;
    if (g < 12500) {
      const float* q = xp + (size_t)g * 12;
      a0 = 0.25f * (q[0] + q[3] + q[6] + q[9]);
      a1 = 0.25f * (q[1] + q[4] + q[7] + q[10]);
      a2 = 0.25f * (q[2] + q[5] + q[8] + q[11]);
    }
    sM[r][0] = a0; sM[r][1] = a1; sM[r][2] = a2;
  }
  __syncthreads();

  // Phase 1: L1 (3 -> 256), fp32 VALU, fp16 into LDS (encode layout)
  {
    int c = tid;
    float w0 = W1[c], w1 = W1[256 + c], w2 = W1[512 + c], bb = b1[c];
#pragma unroll 4
    for (int r = 0; r < 64; ++r) {
      float v = fmaxf(sM[r][0] * w0 + sM[r][1] * w1 + sM[r][2] * w2 + bb, 0.f);
      sA[r * 264 + c] = (_Float16)v;
    }
  }
  __syncthreads();

  // L2: [64x256]@[256x256] relu, encode->encode
  layer<4, 4, 8, true, 0>(Bf + 0,      b2,  sA, nullptr, pair0, wave, lane);
  // L3: [64x256]@[256x256] relu, encode->head (concat)
  layer<4, 4, 8, true, 1>(Bf + 65536,  b3,  sA, nullptr, pair0, wave, lane);
  // H1: [32x512]@[512x512] relu
  layer<2, 8, 16, false, 2>(Bf + 131072, bl1, sA, nullptr, pair0, wave, lane);
  // H2: [32x512]@[512x256] relu
  layer<2, 4, 16, false, 2>(Bf + 393216, bl2, sA, nullptr, pair0, wave, lane);
  // H3: [32x256]@[256x128] relu
  layer<2, 2, 8, false, 2>(Bf + 524288, bl3, sA, nullptr, pair0, wave, lane);
  // H4: [32x128]@[128x64] sigmoid -> global
  layer<2, 1, 4, false, 3>(Bf + 557056, bl4, sA, outg,    pair0, wave, lane);
}

extern "C" void kernel_launch(void* const* d_in, const int* in_sizes, int n_in,
                              void* d_out, int out_size, void* d_ws, size_t ws_size,
                              hipStream_t stream) {
  const float* x1  = (const float*)d_in[0];
  const float* x2  = (const float*)d_in[3];
  const float* W1  = (const float*)d_in[6];
  const float* b1  = (const float*)d_in[7];
  const float* W2  = (const float*)d_in[8];
  const float* b2  = (const float*)d_in[9];
  const float* W3  = (const float*)d_in[10];
  const float* b3  = (const float*)d_in[11];
  const float* Wl1 = (const float*)d_in[12];
  const float* bl1 = (const float*)d_in[13];
  const float* Wl2 = (const float*)d_in[14];
  const float* bl2 = (const float*)d_in[15];
  const float* Wl3 = (const float*)d_in[16];
  const float* bl3 = (const float*)d_in[17];
  const float* Wl4 = (const float*)d_in[18];
  const float* bl4 = (const float*)d_in[19];

  _Float16* Bf = (_Float16*)d_ws;   // 565248 halves = 1.13 MB

  PrepArgsV10 pa;
  pa.in[0] = W2;  pa.in[1] = W3;  pa.in[2] = Wl1;
  pa.in[3] = Wl2; pa.in[4] = Wl3; pa.in[5] = Wl4;

  v10_prep<<<dim3(2208), dim3(256), 0, stream>>>(pa, Bf);
  v10_mega<<<dim3(391), dim3(256), 0, stream>>>(x1, x2, W1, b1, Bf,
                                                b2, b3, bl1, bl2, bl3, bl4,
                                                (float*)d_out);
}